// Round 1
// baseline (1297.730 us; speedup 1.0000x reference)
//
#include <hip/hip_runtime.h>
#include <math.h>

// SQVAE forward, fp32. N=16384 rows, D=512, K=1024 codes, B=8.
#define NROWS 16384
#define DIM   512
#define KCODE 1024

__device__ __forceinline__ float wave_reduce_sum(float v) {
  #pragma unroll
  for (int m = 1; m < 64; m <<= 1) v += __shfl_xor(v, m, 64);
  return v;
}
__device__ __forceinline__ float wave_reduce_max(float v) {
  #pragma unroll
  for (int m = 1; m < 64; m <<= 1) v = fmaxf(v, __shfl_xor(v, m, 64));
  return v;
}
// reduce across 32-lane half (tx groups of the MLP layout)
__device__ __forceinline__ float half_reduce_sum(float v) {
  v += __shfl_xor(v, 1, 64);  v += __shfl_xor(v, 2, 64);
  v += __shfl_xor(v, 4, 64);  v += __shfl_xor(v, 8, 64);
  v += __shfl_xor(v, 16, 64);
  return v;
}

// ---------------------------------------------------------------------------
// Fused MLP layer: Y = LN(relu(X @ W + bias); gamma, beta). Optionally writes
// per-row ||Y||^2 (needed for the distance GEMM when producing z).
// Block tile: 32 rows x 512 cols, BK=16. 256 threads; per thread 4 rows x 16
// cols (cols strided: c = 4*(tx + 32*i)).
// ---------------------------------------------------------------------------
template <bool WRITE_NORM>
__global__ __launch_bounds__(256) void mlp_layer(
    const float* __restrict__ X, const float* __restrict__ W,
    const float* __restrict__ bias, const float* __restrict__ gam,
    const float* __restrict__ bet, float* __restrict__ Y,
    float* __restrict__ rnorm) {
  __shared__ float As[32][20];    // [row][k], padded (20%4==0 keeps f4 stores aligned)
  __shared__ float Bs[16][512];   // [k][col]
  const int t  = threadIdx.x;
  const int tx = t & 31;          // col group
  const int ty = t >> 5;          // row group (0..7), rows ty*4..ty*4+3
  const int row0 = blockIdx.x * 32;

  float4 acc[4][4];
  #pragma unroll
  for (int r = 0; r < 4; ++r)
    #pragma unroll
    for (int i = 0; i < 4; ++i) acc[r][i] = make_float4(0.f, 0.f, 0.f, 0.f);

  for (int kt = 0; kt < DIM; kt += 16) {
    if (t < 128) {  // A tile: 32 rows x 16 k = 128 float4
      const int r = t >> 2, k4 = (t & 3) << 2;
      float4 a = *(const float4*)&X[(size_t)(row0 + r) * DIM + kt + k4];
      *(float4*)&As[r][k4] = a;
    }
    {  // B tile: 16 k-rows x 512 cols = 2048 float4, 8 per thread
      const int kr = t >> 4, c0 = t & 15;
      const float4* src = (const float4*)&W[(size_t)(kt + kr) * DIM];
      float4* dst = (float4*)&Bs[kr][0];
      #pragma unroll
      for (int i = 0; i < 8; ++i) dst[c0 + 16 * i] = src[c0 + 16 * i];
    }
    __syncthreads();
    #pragma unroll
    for (int k = 0; k < 16; ++k) {
      const float a0 = As[ty * 4 + 0][k];
      const float a1 = As[ty * 4 + 1][k];
      const float a2 = As[ty * 4 + 2][k];
      const float a3 = As[ty * 4 + 3][k];
      const float4* brow = (const float4*)&Bs[k][0];
      #pragma unroll
      for (int i = 0; i < 4; ++i) {
        const float4 b = brow[tx + 32 * i];
        acc[0][i].x += a0 * b.x; acc[0][i].y += a0 * b.y; acc[0][i].z += a0 * b.z; acc[0][i].w += a0 * b.w;
        acc[1][i].x += a1 * b.x; acc[1][i].y += a1 * b.y; acc[1][i].z += a1 * b.z; acc[1][i].w += a1 * b.w;
        acc[2][i].x += a2 * b.x; acc[2][i].y += a2 * b.y; acc[2][i].z += a2 * b.z; acc[2][i].w += a2 * b.w;
        acc[3][i].x += a3 * b.x; acc[3][i].y += a3 * b.y; acc[3][i].z += a3 * b.z; acc[3][i].w += a3 * b.w;
      }
    }
    __syncthreads();
  }

  // Epilogue: bias + relu + LayerNorm (+ optional row norm)
  float4 bia[4], g4[4], be4[4];
  #pragma unroll
  for (int i = 0; i < 4; ++i) {
    const int c = 4 * (tx + 32 * i);
    bia[i] = *(const float4*)&bias[c];
    g4[i]  = *(const float4*)&gam[c];
    be4[i] = *(const float4*)&bet[c];
  }
  #pragma unroll
  for (int rr = 0; rr < 4; ++rr) {
    const int row = row0 + ty * 4 + rr;
    float vb[16];
    float s = 0.f, ss = 0.f;
    #pragma unroll
    for (int i = 0; i < 4; ++i) {
      const float4 a = acc[rr][i];
      const float4 b = bia[i];
      const float vv0 = fmaxf(a.x + b.x, 0.f), vv1 = fmaxf(a.y + b.y, 0.f);
      const float vv2 = fmaxf(a.z + b.z, 0.f), vv3 = fmaxf(a.w + b.w, 0.f);
      vb[i * 4 + 0] = vv0; vb[i * 4 + 1] = vv1; vb[i * 4 + 2] = vv2; vb[i * 4 + 3] = vv3;
      s += vv0 + vv1 + vv2 + vv3;
      ss += vv0 * vv0 + vv1 * vv1 + vv2 * vv2 + vv3 * vv3;
    }
    s = half_reduce_sum(s);
    ss = half_reduce_sum(ss);
    const float mean = s * (1.f / 512.f);
    const float var  = ss * (1.f / 512.f) - mean * mean;   // population var, matches jnp.var
    const float rstd = rsqrtf(var + 1e-5f);
    float ns = 0.f;
    #pragma unroll
    for (int i = 0; i < 4; ++i) {
      float4 y;
      y.x = (vb[i * 4 + 0] - mean) * rstd * g4[i].x + be4[i].x;
      y.y = (vb[i * 4 + 1] - mean) * rstd * g4[i].y + be4[i].y;
      y.z = (vb[i * 4 + 2] - mean) * rstd * g4[i].z + be4[i].z;
      y.w = (vb[i * 4 + 3] - mean) * rstd * g4[i].w + be4[i].w;
      if (WRITE_NORM) ns += y.x * y.x + y.y * y.y + y.z * y.z + y.w * y.w;
      *(float4*)&Y[(size_t)row * DIM + 4 * (tx + 32 * i)] = y;
    }
    if (WRITE_NORM) {
      ns = half_reduce_sum(ns);
      if (tx == 0) rnorm[row] = ns;
    }
  }
}

// ---------------------------------------------------------------------------
// cnorm[k] = ||codebook[k]||^2. One wave per row.
// ---------------------------------------------------------------------------
__global__ __launch_bounds__(256) void cnorm_kernel(const float* __restrict__ CB,
                                                    float* __restrict__ cnorm) {
  const int wv = threadIdx.x >> 6, l = threadIdx.x & 63;
  const int r = blockIdx.x * 4 + wv;
  const float* row = &CB[(size_t)r * DIM];
  float s = 0.f;
  #pragma unroll
  for (int j = 0; j < 8; ++j) {
    const float x = row[l + 64 * j];
    s += x * x;
  }
  s = wave_reduce_sum(s);
  if (l == 0) cnorm[r] = s;
}

// ---------------------------------------------------------------------------
// logits[n][k] = -w * (||z_n||^2 + ||c_k||^2 - 2 z_n.c_k)
// 64x64 tile, BK=16, per-thread 4x4.
// ---------------------------------------------------------------------------
__global__ __launch_bounds__(256) void dist_gemm(
    const float* __restrict__ Z, const float* __restrict__ CB,
    const float* __restrict__ znorm, const float* __restrict__ cnorm,
    const float* __restrict__ lpq, float* __restrict__ logits) {
  __shared__ float As[16][68];  // z^T tile
  __shared__ float Bs[16][68];  // c^T tile
  const int t = threadIdx.x;
  const int tx = t & 15, ty = t >> 4;
  const int n0 = blockIdx.y * 64, k0 = blockIdx.x * 64;
  float acc[4][4] = {};

  for (int dt = 0; dt < DIM; dt += 16) {
    const int r = t >> 2, q4 = (t & 3) << 2;
    {
      const float4 a = *(const float4*)&Z[(size_t)(n0 + r) * DIM + dt + q4];
      As[q4 + 0][r] = a.x; As[q4 + 1][r] = a.y; As[q4 + 2][r] = a.z; As[q4 + 3][r] = a.w;
      const float4 b = *(const float4*)&CB[(size_t)(k0 + r) * DIM + dt + q4];
      Bs[q4 + 0][r] = b.x; Bs[q4 + 1][r] = b.y; Bs[q4 + 2][r] = b.z; Bs[q4 + 3][r] = b.w;
    }
    __syncthreads();
    #pragma unroll
    for (int d = 0; d < 16; ++d) {
      const float4 a4 = *(const float4*)&As[d][ty * 4];
      const float4 b4 = *(const float4*)&Bs[d][tx * 4];
      acc[0][0] += a4.x * b4.x; acc[0][1] += a4.x * b4.y; acc[0][2] += a4.x * b4.z; acc[0][3] += a4.x * b4.w;
      acc[1][0] += a4.y * b4.x; acc[1][1] += a4.y * b4.y; acc[1][2] += a4.y * b4.z; acc[1][3] += a4.y * b4.w;
      acc[2][0] += a4.z * b4.x; acc[2][1] += a4.z * b4.y; acc[2][2] += a4.z * b4.z; acc[2][3] += a4.z * b4.w;
      acc[3][0] += a4.w * b4.x; acc[3][1] += a4.w * b4.y; acc[3][2] += a4.w * b4.z; acc[3][3] += a4.w * b4.w;
    }
    __syncthreads();
  }

  const float w = 0.5f / fmaxf(expf(lpq[0]), 1e-10f);
  const float4 cn = *(const float4*)&cnorm[k0 + tx * 4];
  #pragma unroll
  for (int rr = 0; rr < 4; ++rr) {
    const int n = n0 + ty * 4 + rr;
    const float zn = znorm[n];
    float4 o;
    o.x = -w * (zn + cn.x - 2.f * acc[rr][0]);
    o.y = -w * (zn + cn.y - 2.f * acc[rr][1]);
    o.z = -w * (zn + cn.z - 2.f * acc[rr][2]);
    o.w = -w * (zn + cn.w - 2.f * acc[rr][3]);
    *(float4*)&logits[(size_t)n * KCODE + k0 + tx * 4] = o;
  }
}

// ---------------------------------------------------------------------------
// Per-row: log_softmax stats (kld_discrete, colsum of probs) + gumbel-softmax
// encodings written in place over the logits buffer. One wave per row,
// 16 rows per wave, 64 rows per block.
// ---------------------------------------------------------------------------
__global__ __launch_bounds__(256) void softmax_gumbel(
    float* __restrict__ logits, const float* __restrict__ U,
    float* __restrict__ colsum, float* __restrict__ kldd_acc) {
  const int t = threadIdx.x;
  const int wv = t >> 6, l = t & 63;
  float psum[16];
  #pragma unroll
  for (int i = 0; i < 16; ++i) psum[i] = 0.f;
  float kldd = 0.f;
  const int nbase = blockIdx.x * 64 + wv * 16;

  for (int it = 0; it < 16; ++it) {
    const size_t off = (size_t)(nbase + it) * KCODE + 4 * l;
    float v[16];
    #pragma unroll
    for (int j = 0; j < 4; ++j) {
      const float4 t4 = *(const float4*)&logits[off + 256 * j];
      v[4 * j + 0] = t4.x; v[4 * j + 1] = t4.y; v[4 * j + 2] = t4.z; v[4 * j + 3] = t4.w;
    }
    float m = v[0];
    #pragma unroll
    for (int i = 1; i < 16; ++i) m = fmaxf(m, v[i]);
    m = wave_reduce_max(m);
    float se = 0.f;
    #pragma unroll
    for (int i = 0; i < 16; ++i) se += expf(v[i] - m);
    se = wave_reduce_sum(se);
    const float lz = logf(se);
    float pl = 0.f;
    #pragma unroll
    for (int i = 0; i < 16; ++i) {
      const float lp = v[i] - m - lz;
      const float p = expf(lp);
      psum[i] += p;
      pl += p * lp;
    }
    kldd += pl;
    // gumbel noise + softmax of (logit + g)
    float y[16];
    #pragma unroll
    for (int j = 0; j < 4; ++j) {
      const float4 t4 = *(const float4*)&U[off + 256 * j];
      y[4 * j + 0] = v[4 * j + 0] - logf(-logf(t4.x + 1e-10f) + 1e-10f);
      y[4 * j + 1] = v[4 * j + 1] - logf(-logf(t4.y + 1e-10f) + 1e-10f);
      y[4 * j + 2] = v[4 * j + 2] - logf(-logf(t4.z + 1e-10f) + 1e-10f);
      y[4 * j + 3] = v[4 * j + 3] - logf(-logf(t4.w + 1e-10f) + 1e-10f);
    }
    float m2 = y[0];
    #pragma unroll
    for (int i = 1; i < 16; ++i) m2 = fmaxf(m2, y[i]);
    m2 = wave_reduce_max(m2);
    float s2 = 0.f;
    #pragma unroll
    for (int i = 0; i < 16; ++i) s2 += expf(y[i] - m2);
    s2 = wave_reduce_sum(s2);
    const float inv = 1.f / s2;
    #pragma unroll
    for (int j = 0; j < 4; ++j) {
      float4 e;
      e.x = expf(y[4 * j + 0] - m2) * inv;
      e.y = expf(y[4 * j + 1] - m2) * inv;
      e.z = expf(y[4 * j + 2] - m2) * inv;
      e.w = expf(y[4 * j + 3] - m2) * inv;
      *(float4*)&logits[off + 256 * j] = e;
    }
  }
  #pragma unroll
  for (int j = 0; j < 4; ++j)
    #pragma unroll
    for (int c = 0; c < 4; ++c)
      atomicAdd(&colsum[256 * j + 4 * l + c], psum[4 * j + c]);
  kldd = wave_reduce_sum(kldd);
  if (l == 0) atomicAdd(kldd_acc, kldd);
}

// ---------------------------------------------------------------------------
// z_q = encodings @ codebook, fused sum((z - z_q)^2)*w accumulation.
// 64x64 tile, BK=16, per-thread 4x4.
// ---------------------------------------------------------------------------
__global__ __launch_bounds__(256) void zq_gemm(
    const float* __restrict__ E, const float* __restrict__ CB,
    const float* __restrict__ Z, const float* __restrict__ lpq,
    float* __restrict__ ZQ, float* __restrict__ kldc_acc) {
  __shared__ float As[16][68];  // enc^T tile
  __shared__ float Bs[16][68];  // codebook tile (natural)
  const int t = threadIdx.x;
  const int tx = t & 15, ty = t >> 4;
  const int n0 = blockIdx.y * 64, d0 = blockIdx.x * 64;
  float acc[4][4] = {};

  for (int kt = 0; kt < KCODE; kt += 16) {
    {
      const int r = t >> 2, q4 = (t & 3) << 2;
      const float4 a = *(const float4*)&E[(size_t)(n0 + r) * KCODE + kt + q4];
      As[q4 + 0][r] = a.x; As[q4 + 1][r] = a.y; As[q4 + 2][r] = a.z; As[q4 + 3][r] = a.w;
      const int kk = t >> 4, d4 = (t & 15) << 2;
      const float4 b = *(const float4*)&CB[(size_t)(kt + kk) * DIM + d0 + d4];
      *(float4*)&Bs[kk][d4] = b;
    }
    __syncthreads();
    #pragma unroll
    for (int d = 0; d < 16; ++d) {
      const float4 a4 = *(const float4*)&As[d][ty * 4];
      const float4 b4 = *(const float4*)&Bs[d][tx * 4];
      acc[0][0] += a4.x * b4.x; acc[0][1] += a4.x * b4.y; acc[0][2] += a4.x * b4.z; acc[0][3] += a4.x * b4.w;
      acc[1][0] += a4.y * b4.x; acc[1][1] += a4.y * b4.y; acc[1][2] += a4.y * b4.z; acc[1][3] += a4.y * b4.w;
      acc[2][0] += a4.z * b4.x; acc[2][1] += a4.z * b4.y; acc[2][2] += a4.z * b4.z; acc[2][3] += a4.z * b4.w;
      acc[3][0] += a4.w * b4.x; acc[3][1] += a4.w * b4.y; acc[3][2] += a4.w * b4.z; acc[3][3] += a4.w * b4.w;
    }
    __syncthreads();
  }

  const float w = 0.5f / fmaxf(expf(lpq[0]), 1e-10f);
  float local = 0.f;
  #pragma unroll
  for (int rr = 0; rr < 4; ++rr) {
    const int n = n0 + ty * 4 + rr;
    float4 zq;
    zq.x = acc[rr][0]; zq.y = acc[rr][1]; zq.z = acc[rr][2]; zq.w = acc[rr][3];
    const float4 z = *(const float4*)&Z[(size_t)n * DIM + d0 + tx * 4];
    const float dx = z.x - zq.x, dy = z.y - zq.y, dz = z.z - zq.z, dw = z.w - zq.w;
    local += dx * dx + dy * dy + dz * dz + dw * dw;
    *(float4*)&ZQ[(size_t)n * DIM + d0 + tx * 4] = zq;
  }
  local = wave_reduce_sum(local) * w;
  if ((t & 63) == 0) atomicAdd(kldc_acc, local);
}

// ---------------------------------------------------------------------------
// Finalize: perplexity from colsum, loss from scalar accumulators.
// out points at d_out + B*S*D.
// ---------------------------------------------------------------------------
__global__ __launch_bounds__(256) void finalize(
    const float* __restrict__ colsum, const float* __restrict__ scal,
    float* __restrict__ out) {
  const int t = threadIdx.x;
  float ent = 0.f;
  #pragma unroll
  for (int j = 0; j < 4; ++j) {
    const float a = colsum[t + 256 * j] * (1.f / 16384.f);
    ent += a * logf(a + 1e-7f);
  }
  ent = wave_reduce_sum(ent);
  __shared__ float red[4];
  if ((t & 63) == 0) red[t >> 6] = ent;
  __syncthreads();
  if (t == 0) {
    const float tot = red[0] + red[1] + red[2] + red[3];
    out[0] = (scal[0] + scal[1]) * (1.f / 8.f);  // loss = (kld_d + kld_c)/bs
    out[1] = expf(-tot);                          // perplexity
  }
}

extern "C" void kernel_launch(void* const* d_in, const int* in_sizes, int n_in,
                              void* d_out, int out_size, void* d_ws, size_t ws_size,
                              hipStream_t stream) {
  const float* x      = (const float*)d_in[0];
  const float* gu     = (const float*)d_in[1];
  const float* enc_w1 = (const float*)d_in[2];
  const float* enc_b1 = (const float*)d_in[3];
  const float* enc_g1 = (const float*)d_in[4];
  const float* enc_e1 = (const float*)d_in[5];
  const float* enc_w2 = (const float*)d_in[6];
  const float* enc_b2 = (const float*)d_in[7];
  const float* enc_g2 = (const float*)d_in[8];
  const float* enc_e2 = (const float*)d_in[9];
  const float* dec_w1 = (const float*)d_in[10];
  const float* dec_b1 = (const float*)d_in[11];
  const float* dec_g1 = (const float*)d_in[12];
  const float* dec_e1 = (const float*)d_in[13];
  const float* dec_w2 = (const float*)d_in[14];
  const float* dec_b2 = (const float*)d_in[15];
  const float* dec_g2 = (const float*)d_in[16];
  const float* dec_e2 = (const float*)d_in[17];
  const float* cb     = (const float*)d_in[18];
  const float* lpq    = (const float*)d_in[19];
  float* out = (float*)d_out;
  float* ws  = (float*)d_ws;

  float* h      = ws;                       // N*D
  float* z      = ws + 8388608;             // N*D
  float* logits = ws + 16777216;            // N*K (reused as encodings in place)
  float* zq     = ws + 33554432;            // N*D
  float* znorm  = ws + 41943040;            // N
  float* cnorm  = znorm + NROWS;            // K
  float* colsum = cnorm + KCODE;            // K
  float* scal   = colsum + KCODE;           // [kld_d_raw, kld_c_raw]

  hipMemsetAsync(colsum, 0, (KCODE + 2) * sizeof(float), stream);

  cnorm_kernel<<<256, 256, 0, stream>>>(cb, cnorm);
  mlp_layer<false><<<512, 256, 0, stream>>>(x, enc_w1, enc_b1, enc_g1, enc_e1, h, nullptr);
  mlp_layer<true ><<<512, 256, 0, stream>>>(h, enc_w2, enc_b2, enc_g2, enc_e2, z, znorm);
  dist_gemm<<<dim3(KCODE / 64, NROWS / 64), 256, 0, stream>>>(z, cb, znorm, cnorm, lpq, logits);
  softmax_gumbel<<<NROWS / 64, 256, 0, stream>>>(logits, gu, colsum, &scal[0]);
  zq_gemm<<<dim3(DIM / 64, NROWS / 64), 256, 0, stream>>>(logits, cb, z, lpq, zq, &scal[1]);
  mlp_layer<false><<<512, 256, 0, stream>>>(zq, dec_w1, dec_b1, dec_g1, dec_e1, h, nullptr);
  mlp_layer<false><<<512, 256, 0, stream>>>(h, dec_w2, dec_b2, dec_g2, dec_e2, out, nullptr);
  finalize<<<1, 256, 0, stream>>>(colsum, scal, out + 8388608);
}

// Round 2
// 887.647 us; speedup vs baseline: 1.4620x; 1.4620x over previous
//
#include <hip/hip_runtime.h>
#include <math.h>

// SQVAE forward on MI355X. N=16384 rows, D=512, K=1024 codes, B=8.
// GEMMs in bf16 MFMA (16x16x32), dist GEMM uses hi/lo bf16 split for
// fp32-accurate logits. All other math fp32.
#define NROWS 16384
#define DIM   512
#define KCODE 1024

typedef __attribute__((ext_vector_type(8))) __bf16 bf16x8;
typedef __attribute__((ext_vector_type(4))) float f32x4;

__device__ __forceinline__ float wave_reduce_sum(float v) {
  #pragma unroll
  for (int m = 1; m < 64; m <<= 1) v += __shfl_xor(v, m, 64);
  return v;
}
__device__ __forceinline__ float wave_reduce_max(float v) {
  #pragma unroll
  for (int m = 1; m < 64; m <<= 1) v = fmaxf(v, __shfl_xor(v, m, 64));
  return v;
}
__device__ __forceinline__ unsigned short f2bf(float f) {
  union { float f; unsigned u; } v; v.f = f;
  unsigned r = v.u + 0x7FFFu + ((v.u >> 16) & 1u);  // RNE
  return (unsigned short)(r >> 16);
}
__device__ __forceinline__ float bf2f(unsigned short h) {
  union { unsigned u; float f; } v; v.u = ((unsigned)h) << 16;
  return v.f;
}
__device__ __forceinline__ uint4 pack8(const float* x) {
  uint4 r;
  r.x = (unsigned)f2bf(x[0]) | ((unsigned)f2bf(x[1]) << 16);
  r.y = (unsigned)f2bf(x[2]) | ((unsigned)f2bf(x[3]) << 16);
  r.z = (unsigned)f2bf(x[4]) | ((unsigned)f2bf(x[5]) << 16);
  r.w = (unsigned)f2bf(x[6]) | ((unsigned)f2bf(x[7]) << 16);
  return r;
}

// ---------------------------------------------------------------------------
// bf16 MFMA GEMM, C = sum_p A_p @ B_p^T. A: [M][K] bf16 pitch LDA, B: [N][K]
// bf16 pitch K. 128x128 tile, BK=32, 256 threads = 4 waves in 2x2, each wave
// a 4x4 grid of 16x16x32 MFMA tiles. LDS in fragment-linear layout (chunk
// (mi, lane) of 16B) -> conflict-free ds_read_b128, 2-way-free ds_write.
// EPI: 0 = bias+relu -> bf16; 1 = dist logits -> fp32; 2 = zq -> bf16 + kldc.
// ---------------------------------------------------------------------------
template <int NPASS, int EPI, int K, int N, int LDA>
__global__ __launch_bounds__(256) void gemm_bt(
    const unsigned short* A0, const unsigned short* A1, const unsigned short* A2,
    const unsigned short* B0, const unsigned short* B1, const unsigned short* B2,
    const float* __restrict__ bias,
    const float* __restrict__ znorm, const float* __restrict__ cnorm,
    const float* __restrict__ lpq,
    const unsigned short* __restrict__ zh, const unsigned short* __restrict__ zl,
    float* __restrict__ kldc,
    unsigned short* __restrict__ outb, float* __restrict__ outf) {
  __shared__ unsigned short Abuf[128 * 32];
  __shared__ unsigned short Bbuf[128 * 32];
  const int t = threadIdx.x;
  const int l = t & 63, w = t >> 6;
  const int wm = w >> 1, wn = w & 1;
  const int m0 = blockIdx.y * 128, n0 = blockIdx.x * 128;

  f32x4 acc[4][4];
  #pragma unroll
  for (int i = 0; i < 4; ++i)
    #pragma unroll
    for (int j = 0; j < 4; ++j) acc[i][j] = (f32x4){0.f, 0.f, 0.f, 0.f};

  const unsigned short* APs[3] = {A0, A1, A2};
  const unsigned short* BPs[3] = {B0, B1, B2};

  #pragma unroll 1
  for (int p = 0; p < NPASS; ++p) {
    const unsigned short* gA = APs[p];
    const unsigned short* gB = BPs[p];
    for (int kt = 0; kt < K; kt += 32) {
      uint4 va[2], vb[2];
      #pragma unroll
      for (int i = 0; i < 2; ++i) {
        const int c = i * 256 + t;
        const int m = c >> 2, q = c & 3;
        va[i] = *(const uint4*)&gA[(size_t)(m0 + m) * LDA + kt + q * 8];
        vb[i] = *(const uint4*)&gB[(size_t)(n0 + m) * K + kt + q * 8];
      }
      __syncthreads();
      #pragma unroll
      for (int i = 0; i < 2; ++i) {
        const int c = i * 256 + t;
        const int m = c >> 2, q = c & 3;
        const int chunk = (m >> 4) * 64 + (q << 4) + (m & 15);
        *(uint4*)&Abuf[chunk * 8] = va[i];
        *(uint4*)&Bbuf[chunk * 8] = vb[i];
      }
      __syncthreads();
      bf16x8 af[4], bfr[4];
      #pragma unroll
      for (int i = 0; i < 4; ++i) {
        af[i]  = *(const bf16x8*)&Abuf[((wm * 4 + i) * 64 + l) * 8];
        bfr[i] = *(const bf16x8*)&Bbuf[((wn * 4 + i) * 64 + l) * 8];
      }
      #pragma unroll
      for (int mi = 0; mi < 4; ++mi)
        #pragma unroll
        for (int ni = 0; ni < 4; ++ni)
          acc[mi][ni] = __builtin_amdgcn_mfma_f32_16x16x32_bf16(af[mi], bfr[ni], acc[mi][ni], 0, 0, 0);
    }
  }

  const int q = l >> 4, c16 = l & 15;
  if (EPI == 0) {
    #pragma unroll
    for (int ni = 0; ni < 4; ++ni) {
      const int n = n0 + wn * 64 + ni * 16 + c16;
      const float bv = bias[n];
      #pragma unroll
      for (int mi = 0; mi < 4; ++mi)
        #pragma unroll
        for (int r = 0; r < 4; ++r) {
          const int m = m0 + wm * 64 + mi * 16 + q * 4 + r;
          outb[(size_t)m * N + n] = f2bf(fmaxf(acc[mi][ni][r] + bv, 0.f));
        }
    }
  } else if (EPI == 1) {
    const float wq = 0.5f / fmaxf(expf(lpq[0]), 1e-10f);
    #pragma unroll
    for (int mi = 0; mi < 4; ++mi)
      #pragma unroll
      for (int r = 0; r < 4; ++r) {
        const int m = m0 + wm * 64 + mi * 16 + q * 4 + r;
        const float zn = znorm[m];
        #pragma unroll
        for (int ni = 0; ni < 4; ++ni) {
          const int n = n0 + wn * 64 + ni * 16 + c16;
          outf[(size_t)m * N + n] = -wq * (zn + cnorm[n] - 2.f * acc[mi][ni][r]);
        }
      }
  } else {
    const float wq = 0.5f / fmaxf(expf(lpq[0]), 1e-10f);
    float local = 0.f;
    #pragma unroll
    for (int mi = 0; mi < 4; ++mi)
      #pragma unroll
      for (int r = 0; r < 4; ++r) {
        const int m = m0 + wm * 64 + mi * 16 + q * 4 + r;
        #pragma unroll
        for (int ni = 0; ni < 4; ++ni) {
          const int n = n0 + wn * 64 + ni * 16 + c16;
          const float zqv = acc[mi][ni][r];
          const float zv = bf2f(zh[(size_t)m * N + n]) + bf2f(zl[(size_t)m * N + n]);
          const float d = zv - zqv;
          local += d * d;
          outb[(size_t)m * N + n] = f2bf(zqv);
        }
      }
    local = wave_reduce_sum(local) * wq;
    if (l == 0) atomicAdd(kldc, local);
  }
}

// ---------------------------------------------------------------------------
// Row LayerNorm over bf16 input [M][512]. MODE 0: bf16 out. MODE 1: hi/lo
// split out + row norm^2. MODE 2: fp32 out (final x_rec).
// ---------------------------------------------------------------------------
template <int MODE>
__global__ __launch_bounds__(256) void ln_rows(
    const unsigned short* __restrict__ X, const float* __restrict__ g,
    const float* __restrict__ be, unsigned short* __restrict__ Y,
    unsigned short* __restrict__ Yl, float* __restrict__ znorm,
    float* __restrict__ Yf) {
  const int l = threadIdx.x & 63, wv = threadIdx.x >> 6;
  float gv[8], bv[8];
  {
    const float4 a = *(const float4*)&g[l * 8];
    const float4 b = *(const float4*)&g[l * 8 + 4];
    gv[0] = a.x; gv[1] = a.y; gv[2] = a.z; gv[3] = a.w;
    gv[4] = b.x; gv[5] = b.y; gv[6] = b.z; gv[7] = b.w;
    const float4 c = *(const float4*)&be[l * 8];
    const float4 d = *(const float4*)&be[l * 8 + 4];
    bv[0] = c.x; bv[1] = c.y; bv[2] = c.z; bv[3] = c.w;
    bv[4] = d.x; bv[5] = d.y; bv[6] = d.z; bv[7] = d.w;
  }
  const int row0 = blockIdx.x * 32 + wv * 8;
  for (int rr = 0; rr < 8; ++rr) {
    const int row = row0 + rr;
    const uint4 raw = *(const uint4*)&X[(size_t)row * 512 + l * 8];
    float v[8];
    const unsigned rw[4] = {raw.x, raw.y, raw.z, raw.w};
    #pragma unroll
    for (int i = 0; i < 4; ++i) {
      v[2 * i]     = bf2f((unsigned short)(rw[i] & 0xFFFF));
      v[2 * i + 1] = bf2f((unsigned short)(rw[i] >> 16));
    }
    float s = 0.f, ss = 0.f;
    #pragma unroll
    for (int i = 0; i < 8; ++i) { s += v[i]; ss += v[i] * v[i]; }
    #pragma unroll
    for (int m = 1; m < 64; m <<= 1) {
      s += __shfl_xor(s, m, 64);
      ss += __shfl_xor(ss, m, 64);
    }
    const float mean = s * (1.f / 512.f);
    const float var = ss * (1.f / 512.f) - mean * mean;
    const float rstd = rsqrtf(var + 1e-5f);
    float y[8];
    #pragma unroll
    for (int i = 0; i < 8; ++i) y[i] = (v[i] - mean) * rstd * gv[i] + bv[i];
    if (MODE == 0) {
      *(uint4*)&Y[(size_t)row * 512 + l * 8] = pack8(y);
    } else if (MODE == 1) {
      float lo[8], ns = 0.f;
      unsigned short hx[8];
      #pragma unroll
      for (int i = 0; i < 8; ++i) {
        hx[i] = f2bf(y[i]);
        lo[i] = y[i] - bf2f(hx[i]);
        ns += y[i] * y[i];
      }
      uint4 hv;
      hv.x = (unsigned)hx[0] | ((unsigned)hx[1] << 16);
      hv.y = (unsigned)hx[2] | ((unsigned)hx[3] << 16);
      hv.z = (unsigned)hx[4] | ((unsigned)hx[5] << 16);
      hv.w = (unsigned)hx[6] | ((unsigned)hx[7] << 16);
      *(uint4*)&Y[(size_t)row * 512 + l * 8] = hv;
      *(uint4*)&Yl[(size_t)row * 512 + l * 8] = pack8(lo);
      ns = wave_reduce_sum(ns);
      if (l == 0) znorm[row] = ns;
    } else {
      float4 o0, o1;
      o0.x = y[0]; o0.y = y[1]; o0.z = y[2]; o0.w = y[3];
      o1.x = y[4]; o1.y = y[5]; o1.z = y[6]; o1.w = y[7];
      *(float4*)&Yf[(size_t)row * 512 + l * 8] = o0;
      *(float4*)&Yf[(size_t)row * 512 + l * 8 + 4] = o1;
    }
  }
}

// ---------------------------------------------------------------------------
// Prep kernels.
// ---------------------------------------------------------------------------
__global__ __launch_bounds__(256) void convert_f32_bf16(
    const float* __restrict__ X, unsigned short* __restrict__ Y) {
  const size_t i = ((size_t)blockIdx.x * 256 + threadIdx.x) * 8;
  const float4 a = *(const float4*)&X[i];
  const float4 b = *(const float4*)&X[i + 4];
  float v[8] = {a.x, a.y, a.z, a.w, b.x, b.y, b.z, b.w};
  *(uint4*)&Y[i] = pack8(v);
}

// codebook -> hi/lo bf16 + ||c||^2
__global__ __launch_bounds__(256) void prep_cb(
    const float* __restrict__ CB, unsigned short* __restrict__ H,
    unsigned short* __restrict__ L, float* __restrict__ cnorm) {
  const int wv = threadIdx.x >> 6, l = threadIdx.x & 63;
  const int r = blockIdx.x * 4 + wv;
  const float* row = &CB[(size_t)r * 512 + l * 8];
  const float4 a = *(const float4*)row;
  const float4 b = *(const float4*)(row + 4);
  float x[8] = {a.x, a.y, a.z, a.w, b.x, b.y, b.z, b.w};
  float s = 0.f, lo[8];
  unsigned short hi[8];
  #pragma unroll
  for (int i = 0; i < 8; ++i) {
    s += x[i] * x[i];
    hi[i] = f2bf(x[i]);
    lo[i] = x[i] - bf2f(hi[i]);
  }
  uint4 hv;
  hv.x = (unsigned)hi[0] | ((unsigned)hi[1] << 16);
  hv.y = (unsigned)hi[2] | ((unsigned)hi[3] << 16);
  hv.z = (unsigned)hi[4] | ((unsigned)hi[5] << 16);
  hv.w = (unsigned)hi[6] | ((unsigned)hi[7] << 16);
  *(uint4*)&H[(size_t)r * 512 + l * 8] = hv;
  *(uint4*)&L[(size_t)r * 512 + l * 8] = pack8(lo);
  s = wave_reduce_sum(s);
  if (l == 0) cnorm[r] = s;
}

// in [R][C] fp32 -> out [C][R] bf16
__global__ __launch_bounds__(256) void transpose_f32_bf16(
    const float* __restrict__ in, unsigned short* __restrict__ out, int R, int C) {
  const int o = blockIdx.x * 256 + threadIdx.x;
  const int c = o / R, r = o % R;
  out[o] = f2bf(in[(size_t)r * C + c]);
}

// ---------------------------------------------------------------------------
// Softmax stats + gumbel-softmax. Writes encodings bf16 into the first half
// of each logits row (pitch 2048 ushorts). Safe: every stored value depends
// on all loaded values via wave reductions.
// ---------------------------------------------------------------------------
__global__ __launch_bounds__(256) void softmax_gumbel(
    const float* logits, const float* __restrict__ U, unsigned short* E,
    float* __restrict__ colsum, float* __restrict__ kldd_acc) {
  const int t = threadIdx.x;
  const int wv = t >> 6, l = t & 63;
  float psum[16];
  #pragma unroll
  for (int i = 0; i < 16; ++i) psum[i] = 0.f;
  float kldd = 0.f;
  const int nbase = blockIdx.x * 64 + wv * 16;

  for (int it = 0; it < 16; ++it) {
    const int row = nbase + it;
    const size_t off = (size_t)row * KCODE + 4 * l;
    float v[16];
    #pragma unroll
    for (int j = 0; j < 4; ++j) {
      const float4 t4 = *(const float4*)&logits[off + 256 * j];
      v[4 * j + 0] = t4.x; v[4 * j + 1] = t4.y; v[4 * j + 2] = t4.z; v[4 * j + 3] = t4.w;
    }
    float m = v[0];
    #pragma unroll
    for (int i = 1; i < 16; ++i) m = fmaxf(m, v[i]);
    m = wave_reduce_max(m);
    float se = 0.f;
    #pragma unroll
    for (int i = 0; i < 16; ++i) se += expf(v[i] - m);
    se = wave_reduce_sum(se);
    const float lz = logf(se);
    float pl = 0.f;
    #pragma unroll
    for (int i = 0; i < 16; ++i) {
      const float lp = v[i] - m - lz;
      const float p = expf(lp);
      psum[i] += p;
      pl += p * lp;
    }
    kldd += pl;
    float y[16];
    #pragma unroll
    for (int j = 0; j < 4; ++j) {
      const float4 t4 = *(const float4*)&U[off + 256 * j];
      y[4 * j + 0] = v[4 * j + 0] - logf(-logf(t4.x + 1e-10f) + 1e-10f);
      y[4 * j + 1] = v[4 * j + 1] - logf(-logf(t4.y + 1e-10f) + 1e-10f);
      y[4 * j + 2] = v[4 * j + 2] - logf(-logf(t4.z + 1e-10f) + 1e-10f);
      y[4 * j + 3] = v[4 * j + 3] - logf(-logf(t4.w + 1e-10f) + 1e-10f);
    }
    float m2 = y[0];
    #pragma unroll
    for (int i = 1; i < 16; ++i) m2 = fmaxf(m2, y[i]);
    m2 = wave_reduce_max(m2);
    float s2 = 0.f;
    #pragma unroll
    for (int i = 0; i < 16; ++i) s2 += expf(y[i] - m2);
    s2 = wave_reduce_sum(s2);
    const float inv = 1.f / s2;
    #pragma unroll
    for (int j = 0; j < 4; ++j) {
      ushort4 e;
      e.x = f2bf(expf(y[4 * j + 0] - m2) * inv);
      e.y = f2bf(expf(y[4 * j + 1] - m2) * inv);
      e.z = f2bf(expf(y[4 * j + 2] - m2) * inv);
      e.w = f2bf(expf(y[4 * j + 3] - m2) * inv);
      *(ushort4*)&E[(size_t)row * 2048 + 4 * l + 256 * j] = e;
    }
  }
  #pragma unroll
  for (int j = 0; j < 4; ++j)
    #pragma unroll
    for (int c = 0; c < 4; ++c)
      atomicAdd(&colsum[256 * j + 4 * l + c], psum[4 * j + c]);
  kldd = wave_reduce_sum(kldd);
  if (l == 0) atomicAdd(kldd_acc, kldd);
}

__global__ __launch_bounds__(256) void finalize(
    const float* __restrict__ colsum, const float* __restrict__ scal,
    float* __restrict__ out) {
  const int t = threadIdx.x;
  float ent = 0.f;
  #pragma unroll
  for (int j = 0; j < 4; ++j) {
    const float a = colsum[t + 256 * j] * (1.f / 16384.f);
    ent += a * logf(a + 1e-7f);
  }
  ent = wave_reduce_sum(ent);
  __shared__ float red[4];
  if ((t & 63) == 0) red[t >> 6] = ent;
  __syncthreads();
  if (t == 0) {
    const float tot = red[0] + red[1] + red[2] + red[3];
    out[0] = (scal[0] + scal[1]) * (1.f / 8.f);
    out[1] = expf(-tot);
  }
}

extern "C" void kernel_launch(void* const* d_in, const int* in_sizes, int n_in,
                              void* d_out, int out_size, void* d_ws, size_t ws_size,
                              hipStream_t stream) {
  const float* x      = (const float*)d_in[0];
  const float* gu     = (const float*)d_in[1];
  const float* enc_w1 = (const float*)d_in[2];
  const float* enc_b1 = (const float*)d_in[3];
  const float* enc_g1 = (const float*)d_in[4];
  const float* enc_e1 = (const float*)d_in[5];
  const float* enc_w2 = (const float*)d_in[6];
  const float* enc_b2 = (const float*)d_in[7];
  const float* enc_g2 = (const float*)d_in[8];
  const float* enc_e2 = (const float*)d_in[9];
  const float* dec_w1 = (const float*)d_in[10];
  const float* dec_b1 = (const float*)d_in[11];
  const float* dec_g1 = (const float*)d_in[12];
  const float* dec_e1 = (const float*)d_in[13];
  const float* dec_w2 = (const float*)d_in[14];
  const float* dec_b2 = (const float*)d_in[15];
  const float* dec_g2 = (const float*)d_in[16];
  const float* dec_e2 = (const float*)d_in[17];
  const float* cb     = (const float*)d_in[18];
  const float* lpq    = (const float*)d_in[19];
  float* out = (float*)d_out;
  char* wsb = (char*)d_ws;

  float*          logits = (float*)(wsb + 0);                 // 67108864 B
  unsigned short* Eb     = (unsigned short*)(wsb + 0);        // overlay, pitch 2048
  unsigned short* t1     = (unsigned short*)(wsb + 67108864); // 16 MB
  unsigned short* xb     = (unsigned short*)(wsb + 83886080); // 16 MB (xb then zh)
  unsigned short* zh     = xb;
  unsigned short* hq     = (unsigned short*)(wsb + 100663296); // 16 MB (h then zq)
  unsigned short* zl     = (unsigned short*)(wsb + 117440512); // 16 MB (zl then h2)
  unsigned short* wt0    = (unsigned short*)(wsb + 134217728);
  unsigned short* wt1    = wt0 + 262144;
  unsigned short* wt2    = wt1 + 262144;
  unsigned short* wt3    = wt2 + 262144;
  unsigned short* cbh    = (unsigned short*)(wsb + 136314880);
  unsigned short* cbl    = (unsigned short*)(wsb + 137363456);
  unsigned short* cbT    = (unsigned short*)(wsb + 138412032);
  float*          znorm  = (float*)(wsb + 139460608);
  float*          cnorm  = (float*)(wsb + 139526144);
  float*          colsum = (float*)(wsb + 139530240);
  float*          scal   = (float*)(wsb + 139534336);

  hipMemsetAsync(colsum, 0, 4096 + 16, stream);

  convert_f32_bf16<<<4096, 256, 0, stream>>>(x, xb);
  prep_cb<<<256, 256, 0, stream>>>(cb, cbh, cbl, cnorm);
  transpose_f32_bf16<<<1024, 256, 0, stream>>>(enc_w1, wt0, 512, 512);
  transpose_f32_bf16<<<1024, 256, 0, stream>>>(enc_w2, wt1, 512, 512);
  transpose_f32_bf16<<<1024, 256, 0, stream>>>(dec_w1, wt2, 512, 512);
  transpose_f32_bf16<<<1024, 256, 0, stream>>>(dec_w2, wt3, 512, 512);
  transpose_f32_bf16<<<2048, 256, 0, stream>>>(cb, cbT, 1024, 512);

  gemm_bt<1, 0, 512, 512, 512><<<dim3(4, 128), 256, 0, stream>>>(
      xb, nullptr, nullptr, wt0, nullptr, nullptr, enc_b1,
      nullptr, nullptr, nullptr, nullptr, nullptr, nullptr, t1, nullptr);
  ln_rows<0><<<512, 256, 0, stream>>>(t1, enc_g1, enc_e1, hq, nullptr, nullptr, nullptr);
  gemm_bt<1, 0, 512, 512, 512><<<dim3(4, 128), 256, 0, stream>>>(
      hq, nullptr, nullptr, wt1, nullptr, nullptr, enc_b2,
      nullptr, nullptr, nullptr, nullptr, nullptr, nullptr, t1, nullptr);
  ln_rows<1><<<512, 256, 0, stream>>>(t1, enc_g2, enc_e2, zh, zl, znorm, nullptr);
  gemm_bt<3, 1, 512, 1024, 512><<<dim3(8, 128), 256, 0, stream>>>(
      zh, zl, zh, cbh, cbh, cbl, nullptr,
      znorm, cnorm, lpq, nullptr, nullptr, nullptr, nullptr, logits);
  softmax_gumbel<<<256, 256, 0, stream>>>(logits, gu, Eb, colsum, &scal[0]);
  gemm_bt<1, 2, 1024, 512, 2048><<<dim3(4, 128), 256, 0, stream>>>(
      Eb, nullptr, nullptr, cbT, nullptr, nullptr, nullptr,
      nullptr, nullptr, lpq, zh, zl, &scal[1], hq, nullptr);
  gemm_bt<1, 0, 512, 512, 512><<<dim3(4, 128), 256, 0, stream>>>(
      hq, nullptr, nullptr, wt2, nullptr, nullptr, dec_b1,
      nullptr, nullptr, nullptr, nullptr, nullptr, nullptr, t1, nullptr);
  ln_rows<0><<<512, 256, 0, stream>>>(t1, dec_g1, dec_e1, zl, nullptr, nullptr, nullptr);
  gemm_bt<1, 0, 512, 512, 512><<<dim3(4, 128), 256, 0, stream>>>(
      zl, nullptr, nullptr, wt3, nullptr, nullptr, dec_b2,
      nullptr, nullptr, nullptr, nullptr, nullptr, nullptr, t1, nullptr);
  ln_rows<2><<<512, 256, 0, stream>>>(t1, dec_g2, dec_e2, nullptr, nullptr, nullptr, out);
  finalize<<<1, 256, 0, stream>>>(colsum, scal, out + 8388608);
}